// Round 3
// baseline (9785.217 us; speedup 1.0000x reference)
//
#include <hip/hip_runtime.h>
#include <hip/hip_bf16.h>
#include <hip/hip_cooperative_groups.h>

namespace cg = cooperative_groups;

#define B    256
#define S    192
#define F    64
#define HD   1024
#define PRED 48
#define TSTART (S - 1 - PRED)   // 143

typedef __attribute__((ext_vector_type(8))) short short8;
typedef __attribute__((ext_vector_type(4))) float f32x4;

static __device__ __forceinline__ short f2bf(float f) {
    __hip_bfloat16 h = __float2bfloat16(f);
    return *reinterpret_cast<short*>(&h);
}

// ---------------------------------------------------------------------------
// fold_kernel: Wfold[f][n] = sum_hd W_hidden[f][hd] * Wih0[hd][n]   (fp32)
// ---------------------------------------------------------------------------
__global__ void fold_kernel(const float* __restrict__ Wh,
                            const float* __restrict__ Wih0,
                            float* __restrict__ Wfold) {
    const int n  = (blockIdx.x & 3) * 256 + threadIdx.x;
    const int f0 = (blockIdx.x >> 2) * 4;
    float a0 = 0.f, a1 = 0.f, a2 = 0.f, a3 = 0.f;
#pragma unroll 8
    for (int k = 0; k < HD; ++k) {
        const float w = Wih0[(size_t)k * HD + n];
        a0 += Wh[(f0 + 0) * HD + k] * w;
        a1 += Wh[(f0 + 1) * HD + k] * w;
        a2 += Wh[(f0 + 2) * HD + k] * w;
        a3 += Wh[(f0 + 3) * HD + k] * w;
    }
    Wfold[(f0 + 0) * HD + n] = a0;
    Wfold[(f0 + 1) * HD + n] = a1;
    Wfold[(f0 + 2) * HD + n] = a2;
    Wfold[(f0 + 3) * HD + n] = a3;
}

// ---------------------------------------------------------------------------
// bias_kernel: bf0[n] = b_hidden@Wih0[:,n] + bih0[n] + bhh0[n]; bf1 = bih1+bhh1
// ---------------------------------------------------------------------------
__global__ void bias_kernel(const float* __restrict__ bh,
                            const float* __restrict__ Wih0,
                            const float* __restrict__ bih,
                            const float* __restrict__ bhh,
                            float* __restrict__ bf0,
                            float* __restrict__ bf1) {
    const int n = blockIdx.x * 256 + threadIdx.x;
    float a = 0.f;
#pragma unroll 8
    for (int k = 0; k < HD; ++k) a += bh[k] * Wih0[(size_t)k * HD + n];
    bf0[n] = a + bih[n] + bhh[n];
    bf1[n] = bih[HD + n] + bhh[HD + n];
}

// ---------------------------------------------------------------------------
// transpose_cast: src fp32 [K][N] -> dst bf16 [N][K].  64x64 LDS tiles.
// ---------------------------------------------------------------------------
__global__ void transpose_cast(const float* __restrict__ src,
                               short* __restrict__ dst, int K, int N) {
    __shared__ float tile[64][65];
    const int nk = K >> 6;
    const int bk = blockIdx.x % nk;
    const int bn = blockIdx.x / nk;
    const int i  = threadIdx.x;
    {
        const int c4 = (i & 15) * 4;
        for (int it = 0; it < 4; ++it) {
            const int k = (i >> 4) + it * 16;
            const float4 v = *reinterpret_cast<const float4*>(
                &src[(size_t)(bk * 64 + k) * N + bn * 64 + c4]);
            tile[k][c4 + 0] = v.x; tile[k][c4 + 1] = v.y;
            tile[k][c4 + 2] = v.z; tile[k][c4 + 3] = v.w;
        }
    }
    __syncthreads();
    {
        const int n  = i >> 2;
        const int kb = (i & 3) * 16;
        short* dp = &dst[(size_t)(bn * 64 + n) * K + bk * 64 + kb];
#pragma unroll
        for (int j = 0; j < 16; ++j) dp[j] = f2bf(tile[kb + j][n]);
    }
}

// ---------------------------------------------------------------------------
// xcast: x fp32 [B][S][F] -> bf16 same layout
// ---------------------------------------------------------------------------
__global__ void xcast(const float* __restrict__ x, short* __restrict__ xb) {
    const size_t i = ((size_t)blockIdx.x * 256 + threadIdx.x) * 4;
    const float4 v = *reinterpret_cast<const float4*>(&x[i]);
    short4 o;
    o.x = f2bf(v.x); o.y = f2bf(v.y); o.z = f2bf(v.z); o.w = f2bf(v.w);
    *reinterpret_cast<short4*>(&xb[i]) = o;
}

// ---------------------------------------------------------------------------
// K=1024 bf16 MFMA GEMM accumulate: A row-major [.][HD], B pre-transposed
// [N][HD]. Lane layout: 16x16x32 frags, lane = lr + 16*kg.
// ---------------------------------------------------------------------------
static __device__ __forceinline__ f32x4 gemm_k1024(
    const short* __restrict__ A, const short* __restrict__ Bw,
    int arow, int bcol, int kg, f32x4 acc) {
    const short* ap = A + (size_t)arow * HD + kg * 8;
    const short* bp = Bw + (size_t)bcol * HD + kg * 8;
#pragma unroll 8
    for (int k0 = 0; k0 < HD; k0 += 32) {
        const short8 a = *reinterpret_cast<const short8*>(ap + k0);
        const short8 b = *reinterpret_cast<const short8*>(bp + k0);
        acc = __builtin_amdgcn_mfma_f32_16x16x32_bf16(a, b, acc, 0, 0, 0);
    }
    return acc;
}

// ---------------------------------------------------------------------------
// Persistent cooperative kernel: 192 skewed phases, 1 grid-sync each.
// Phase k: waves 0-3 compute h0(k) (k<=190); waves 4-7 compute h1(k-1) (k>=1).
// Block tiling: rt = bid>>5 (8 row groups of 32), ct = XCD-grouped (32 col
// groups of 32). Per-XCD weight-row footprint ~768KB -> L2-resident.
// Afterwards: batched output GEMM over relu'd top-layer history.
// ---------------------------------------------------------------------------
__global__ __launch_bounds__(512) void rnn_persistent(
    const short* __restrict__ xbf,
    const short* __restrict__ WfoldT, const float* __restrict__ bf0,
    const short* __restrict__ WhhT0, const short* __restrict__ WihT1,
    const short* __restrict__ WhhT1, const float* __restrict__ bf1,
    short* h0p0, short* h0p1, short* h1p0, short* h1p1,
    short* Hbuf, const short* __restrict__ WoT,
    const float* __restrict__ bo, float* __restrict__ out) {

    cg::grid_group grid = cg::this_grid();

    short* h0buf[2] = {h0p0, h0p1};
    short* h1buf[2] = {h1p0, h1p1};

    const int bid = blockIdx.x;
    const int ct  = (bid & 7) * 4 + ((bid >> 3) & 3);  // 0..31, XCD-grouped
    const int rt  = bid >> 5;                          // 0..7
    const int w   = threadIdx.x >> 6;                  // 0..7
    const int role = w >> 2;                           // 0: h0-layer, 1: h1-layer
    const int wv  = w & 3;
    const int l   = threadIdx.x & 63;
    const int lr  = l & 15, kg = l >> 4;
    const int m0  = rt * 32 + (wv & 1) * 16;
    const int n0  = ct * 32 + (wv >> 1) * 16;
    const int arow = m0 + lr, bcol = n0 + lr;
    const int rb   = m0 + kg * 4;

    for (int k = 0; k < S; ++k) {
        if (role == 0) {
            if (k < S - 1) {
                f32x4 acc = {0.f, 0.f, 0.f, 0.f};
                // x-path: K=64
                const short* xp = xbf + ((size_t)arow * S + k) * F + kg * 8;
                const short8 a0 = *reinterpret_cast<const short8*>(xp);
                const short8 a1 = *reinterpret_cast<const short8*>(xp + 32);
                const short* bp = WfoldT + (size_t)bcol * F + kg * 8;
                const short8 b0 = *reinterpret_cast<const short8*>(bp);
                const short8 b1 = *reinterpret_cast<const short8*>(bp + 32);
                acc = __builtin_amdgcn_mfma_f32_16x16x32_bf16(a0, b0, acc, 0, 0, 0);
                acc = __builtin_amdgcn_mfma_f32_16x16x32_bf16(a1, b1, acc, 0, 0, 0);
                if (k > 0)
                    acc = gemm_k1024(h0buf[(k - 1) & 1], WhhT0, arow, bcol, kg, acc);
                const float bb = bf0[bcol];
                short* hd = h0buf[k & 1];
#pragma unroll
                for (int r = 0; r < 4; ++r)
                    hd[(size_t)(rb + r) * HD + bcol] = f2bf(tanhf(acc[r] + bb));
            }
        } else {
            if (k >= 1) {
                const int t = k - 1;
                f32x4 acc = {0.f, 0.f, 0.f, 0.f};
                acc = gemm_k1024(h0buf[(k - 1) & 1], WihT1, arow, bcol, kg, acc);
                if (t > 0)
                    acc = gemm_k1024(h1buf[k & 1], WhhT1, arow, bcol, kg, acc);
                const float bb = bf1[bcol];
                short* hd = h1buf[(k - 1) & 1];
#pragma unroll
                for (int r = 0; r < 4; ++r) {
                    const float v = tanhf(acc[r] + bb);
                    hd[(size_t)(rb + r) * HD + bcol] = f2bf(v);
                    if (t >= TSTART) {
                        const float rv = v > 0.f ? v : 0.f;
                        Hbuf[((size_t)(rb + r) * PRED + (t - TSTART)) * HD + bcol] = f2bf(rv);
                    }
                }
            }
        }
        grid.sync();
    }

    // ---- batched output projection: [12288 x 64] = relu(H) @ WoT + bo ----
    const int g = bid * 8 + w;            // 0..2047, need 768
    if (g < 768) {
        f32x4 acc[4] = {{0.f,0.f,0.f,0.f},{0.f,0.f,0.f,0.f},
                        {0.f,0.f,0.f,0.f},{0.f,0.f,0.f,0.f}};
        const int am = g * 16 + lr;
        const short* ap = Hbuf + (size_t)am * HD + kg * 8;
        const short* bp = WoT + (size_t)lr * HD + kg * 8;
#pragma unroll 4
        for (int k0 = 0; k0 < HD; k0 += 32) {
            const short8 a = *reinterpret_cast<const short8*>(ap + k0);
#pragma unroll
            for (int c = 0; c < 4; ++c) {
                const short8 b = *reinterpret_cast<const short8*>(
                    bp + (size_t)c * 16 * HD + k0);
                acc[c] = __builtin_amdgcn_mfma_f32_16x16x32_bf16(a, b, acc[c], 0, 0, 0);
            }
        }
        const int rbg = g * 16 + kg * 4;
#pragma unroll
        for (int c = 0; c < 4; ++c) {
            const float bb = bo[c * 16 + lr];
#pragma unroll
            for (int r = 0; r < 4; ++r)
                out[(size_t)(rbg + r) * F + c * 16 + lr] = acc[c][r] + bb;
        }
    }
}

// ---------------------------------------------------------------------------
extern "C" void kernel_launch(void* const* d_in, const int* in_sizes, int n_in,
                              void* d_out, int out_size, void* d_ws, size_t ws_size,
                              hipStream_t stream) {
    const float* x   = (const float*)d_in[0];
    const float* Wh  = (const float*)d_in[1];
    const float* bh  = (const float*)d_in[2];
    const float* Wih = (const float*)d_in[3];
    const float* Whh = (const float*)d_in[4];
    const float* bih = (const float*)d_in[5];
    const float* bhh = (const float*)d_in[6];
    const float* Wo  = (const float*)d_in[7];
    const float* bo  = (const float*)d_in[8];
    float* out = (float*)d_out;

    char* p = (char*)d_ws;
    float* Wfold  = (float*)p; p += (size_t)F * HD * 4;          // 256 KB
    float* bf0    = (float*)p; p += HD * 4;
    float* bf1    = (float*)p; p += HD * 4;
    short* WfoldT = (short*)p; p += (size_t)HD * F * 2;          // 128 KB
    short* WhhT0  = (short*)p; p += (size_t)HD * HD * 2;         // 2 MB
    short* WihT1  = (short*)p; p += (size_t)HD * HD * 2;
    short* WhhT1  = (short*)p; p += (size_t)HD * HD * 2;
    short* WoT    = (short*)p; p += (size_t)F * HD * 2;          // 128 KB
    short* h0p0   = (short*)p; p += (size_t)B * HD * 2;
    short* h0p1   = (short*)p; p += (size_t)B * HD * 2;
    short* h1p0   = (short*)p; p += (size_t)B * HD * 2;
    short* h1p1   = (short*)p; p += (size_t)B * HD * 2;          // 4 x 512 KB
    short* Hbuf   = (short*)p; p += (size_t)B * PRED * HD * 2;   // 24 MB
    short* xbf    = (short*)p; p += (size_t)B * S * F * 2;       // 6 MB

    // ---- prep ----
    fold_kernel<<<64, 256, 0, stream>>>(Wh, Wih, Wfold);
    bias_kernel<<<4, 256, 0, stream>>>(bh, Wih, bih, bhh, bf0, bf1);
    transpose_cast<<<16, 256, 0, stream>>>(Wfold, WfoldT, F, HD);
    transpose_cast<<<256, 256, 0, stream>>>(Whh, WhhT0, HD, HD);
    transpose_cast<<<256, 256, 0, stream>>>(Wih + (size_t)HD * HD, WihT1, HD, HD);
    transpose_cast<<<256, 256, 0, stream>>>(Whh + (size_t)HD * HD, WhhT1, HD, HD);
    transpose_cast<<<16, 256, 0, stream>>>(Wo, WoT, HD, F);
    xcast<<<(B * S * F) / (256 * 4), 256, 0, stream>>>(x, xbf);

    // ---- persistent skewed recurrence + fused output GEMM ----
    void* args[] = {
        (void*)&xbf, (void*)&WfoldT, (void*)&bf0, (void*)&WhhT0,
        (void*)&WihT1, (void*)&WhhT1, (void*)&bf1,
        (void*)&h0p0, (void*)&h0p1, (void*)&h1p0, (void*)&h1p1,
        (void*)&Hbuf, (void*)&WoT, (void*)&bo, (void*)&out
    };
    hipLaunchCooperativeKernel((void*)rnn_persistent, dim3(256), dim3(512),
                               args, 0, stream);
}

// Round 4
// 7070.077 us; speedup vs baseline: 1.3840x; 1.3840x over previous
//
#include <hip/hip_runtime.h>
#include <hip/hip_bf16.h>

#define B    256
#define S    192
#define F    64
#define HD   1024
#define PRED 48
#define TSTART (S - 1 - PRED)   // 143
#define NBLK 256

typedef __attribute__((ext_vector_type(8))) short short8;
typedef __attribute__((ext_vector_type(4))) float f32x4;
typedef unsigned long long u64;
typedef unsigned int u32;

static __device__ __forceinline__ short f2bf(float f) {
    __hip_bfloat16 h = __float2bfloat16(f);
    return *reinterpret_cast<short*>(&h);
}

// Coherent (device-scope, MALL-serviced) state access: compiles to
// global_load_dwordx2 / global_store_short with sc1 — no cache maintenance,
// so weights stay L2-resident across all phases.
static __device__ __forceinline__ short8 ld_state(const short* p) {
    union { u64 u[2]; short8 s; } v;
    v.u[0] = __hip_atomic_load((const u64*)p, __ATOMIC_RELAXED,
                               __HIP_MEMORY_SCOPE_AGENT);
    v.u[1] = __hip_atomic_load((const u64*)(p + 4), __ATOMIC_RELAXED,
                               __HIP_MEMORY_SCOPE_AGENT);
    return v.s;
}
static __device__ __forceinline__ void st_state(short* p, short v) {
    __hip_atomic_store(p, v, __ATOMIC_RELAXED, __HIP_MEMORY_SCOPE_AGENT);
}

// ---------------------------------------------------------------------------
// prep kernels (unchanged from round 2/3)
// ---------------------------------------------------------------------------
__global__ void fold_kernel(const float* __restrict__ Wh,
                            const float* __restrict__ Wih0,
                            float* __restrict__ Wfold) {
    const int n  = (blockIdx.x & 3) * 256 + threadIdx.x;
    const int f0 = (blockIdx.x >> 2) * 4;
    float a0 = 0.f, a1 = 0.f, a2 = 0.f, a3 = 0.f;
#pragma unroll 8
    for (int k = 0; k < HD; ++k) {
        const float w = Wih0[(size_t)k * HD + n];
        a0 += Wh[(f0 + 0) * HD + k] * w;
        a1 += Wh[(f0 + 1) * HD + k] * w;
        a2 += Wh[(f0 + 2) * HD + k] * w;
        a3 += Wh[(f0 + 3) * HD + k] * w;
    }
    Wfold[(f0 + 0) * HD + n] = a0;
    Wfold[(f0 + 1) * HD + n] = a1;
    Wfold[(f0 + 2) * HD + n] = a2;
    Wfold[(f0 + 3) * HD + n] = a3;
}

__global__ void bias_kernel(const float* __restrict__ bh,
                            const float* __restrict__ Wih0,
                            const float* __restrict__ bih,
                            const float* __restrict__ bhh,
                            float* __restrict__ bf0,
                            float* __restrict__ bf1) {
    const int n = blockIdx.x * 256 + threadIdx.x;
    float a = 0.f;
#pragma unroll 8
    for (int k = 0; k < HD; ++k) a += bh[k] * Wih0[(size_t)k * HD + n];
    bf0[n] = a + bih[n] + bhh[n];
    bf1[n] = bih[HD + n] + bhh[HD + n];
}

__global__ void transpose_cast(const float* __restrict__ src,
                               short* __restrict__ dst, int K, int N) {
    __shared__ float tile[64][65];
    const int nk = K >> 6;
    const int bk = blockIdx.x % nk;
    const int bn = blockIdx.x / nk;
    const int i  = threadIdx.x;
    {
        const int c4 = (i & 15) * 4;
        for (int it = 0; it < 4; ++it) {
            const int k = (i >> 4) + it * 16;
            const float4 v = *reinterpret_cast<const float4*>(
                &src[(size_t)(bk * 64 + k) * N + bn * 64 + c4]);
            tile[k][c4 + 0] = v.x; tile[k][c4 + 1] = v.y;
            tile[k][c4 + 2] = v.z; tile[k][c4 + 3] = v.w;
        }
    }
    __syncthreads();
    {
        const int n  = i >> 2;
        const int kb = (i & 3) * 16;
        short* dp = &dst[(size_t)(bn * 64 + n) * K + bk * 64 + kb];
#pragma unroll
        for (int j = 0; j < 16; ++j) dp[j] = f2bf(tile[kb + j][n]);
    }
}

__global__ void xcast(const float* __restrict__ x, short* __restrict__ xb) {
    const size_t i = ((size_t)blockIdx.x * 256 + threadIdx.x) * 4;
    const float4 v = *reinterpret_cast<const float4*>(&x[i]);
    short4 o;
    o.x = f2bf(v.x); o.y = f2bf(v.y); o.z = f2bf(v.z); o.w = f2bf(v.w);
    *reinterpret_cast<short4*>(&xb[i]) = o;
}

// ---------------------------------------------------------------------------
// K=1024 GEMM accumulate; A = hidden state via coherent sc1 loads,
// B = weight (pre-transposed [N][K]) via normal cached (L2-hot) loads.
// ---------------------------------------------------------------------------
static __device__ __forceinline__ f32x4 gemm_state(
    const short* A, const short* __restrict__ Bw,
    int arow, int bcol, int kg, f32x4 acc) {
    const short* ap = A + (size_t)arow * HD + kg * 8;
    const short* bp = Bw + (size_t)bcol * HD + kg * 8;
#pragma unroll 8
    for (int k0 = 0; k0 < HD; k0 += 32) {
        const short8 a = ld_state(ap + k0);
        const short8 b = *reinterpret_cast<const short8*>(bp + k0);
        acc = __builtin_amdgcn_mfma_f32_16x16x32_bf16(a, b, acc, 0, 0, 0);
    }
    return acc;
}

// Monotonic-counter grid barrier. No release/acquire fences anywhere —
// visibility of state comes from sc1 stores + __syncthreads' vmcnt(0) drain.
static __device__ __forceinline__ void gridbar(u32* ctr, u32* epoch, u32 target) {
    __syncthreads();   // per-wave s_waitcnt vmcnt(0) before s_barrier: sc1 stores done
    if (threadIdx.x == 0) {
        const u32 a = __hip_atomic_fetch_add(ctr, 1u, __ATOMIC_RELAXED,
                                             __HIP_MEMORY_SCOPE_AGENT);
        if (a == target * NBLK - 1u) {
            __hip_atomic_store(epoch, target, __ATOMIC_RELAXED,
                               __HIP_MEMORY_SCOPE_AGENT);
        } else {
            while (__hip_atomic_load(epoch, __ATOMIC_RELAXED,
                                     __HIP_MEMORY_SCOPE_AGENT) < target)
                __builtin_amdgcn_s_sleep(2);
        }
    }
    __syncthreads();
}

// ---------------------------------------------------------------------------
// Persistent skewed recurrence: phase k: waves 0-3 -> h0(k), waves 4-7 ->
// h1(k-1). Weights in L2 (never invalidated), h-state via MALL (sc1).
// ---------------------------------------------------------------------------
__global__ __launch_bounds__(512) void rnn_persistent(
    const short* __restrict__ xbf,
    const short* __restrict__ WfoldT, const float* __restrict__ bf0,
    const short* __restrict__ WhhT0, const short* __restrict__ WihT1,
    const short* __restrict__ WhhT1, const float* __restrict__ bf1,
    short* h0p0, short* h0p1, short* h1p0, short* h1p1,
    short* Hbuf, u32* ctr, u32* epoch) {

    short* h0buf[2] = {h0p0, h0p1};
    short* h1buf[2] = {h1p0, h1p1};

    const int bid = blockIdx.x;
    const int ct  = (bid & 7) * 4 + ((bid >> 3) & 3);  // 0..31, XCD-grouped
    const int rt  = bid >> 5;                          // 0..7
    const int w   = threadIdx.x >> 6;                  // 0..7
    const int role = w >> 2;                           // 0: layer0, 1: layer1
    const int wv  = w & 3;
    const int l   = threadIdx.x & 63;
    const int lr  = l & 15, kg = l >> 4;
    const int m0  = rt * 32 + (wv & 1) * 16;
    const int n0  = ct * 32 + (wv >> 1) * 16;
    const int arow = m0 + lr, bcol = n0 + lr;
    const int rb   = m0 + kg * 4;

    for (int k = 0; k < S; ++k) {
        if (role == 0) {
            if (k < S - 1) {
                f32x4 acc = {0.f, 0.f, 0.f, 0.f};
                // x-path: K=64 (x, Wfold are read-only, normal cached loads)
                const short* xp = xbf + ((size_t)arow * S + k) * F + kg * 8;
                const short8 a0 = *reinterpret_cast<const short8*>(xp);
                const short8 a1 = *reinterpret_cast<const short8*>(xp + 32);
                const short* bp = WfoldT + (size_t)bcol * F + kg * 8;
                const short8 b0 = *reinterpret_cast<const short8*>(bp);
                const short8 b1 = *reinterpret_cast<const short8*>(bp + 32);
                acc = __builtin_amdgcn_mfma_f32_16x16x32_bf16(a0, b0, acc, 0, 0, 0);
                acc = __builtin_amdgcn_mfma_f32_16x16x32_bf16(a1, b1, acc, 0, 0, 0);
                if (k > 0)
                    acc = gemm_state(h0buf[(k - 1) & 1], WhhT0, arow, bcol, kg, acc);
                const float bb = bf0[bcol];
                short* hd = h0buf[k & 1];
#pragma unroll
                for (int r = 0; r < 4; ++r)
                    st_state(&hd[(size_t)(rb + r) * HD + bcol],
                             f2bf(tanhf(acc[r] + bb)));
            }
        } else {
            if (k >= 1) {
                const int t = k - 1;
                f32x4 acc = {0.f, 0.f, 0.f, 0.f};
                acc = gemm_state(h0buf[(k - 1) & 1], WihT1, arow, bcol, kg, acc);
                if (t > 0)
                    acc = gemm_state(h1buf[k & 1], WhhT1, arow, bcol, kg, acc);
                const float bb = bf1[bcol];
                short* hd = h1buf[(k - 1) & 1];
#pragma unroll
                for (int r = 0; r < 4; ++r) {
                    const float v = tanhf(acc[r] + bb);
                    st_state(&hd[(size_t)(rb + r) * HD + bcol], f2bf(v));
                    if (t >= TSTART) {
                        const float rv = v > 0.f ? v : 0.f;
                        // plain store: flushed at kernel end, read by outgemm
                        Hbuf[((size_t)(rb + r) * PRED + (t - TSTART)) * HD + bcol]
                            = f2bf(rv);
                    }
                }
            }
        }
        if (k < S - 1) gridbar(ctr, epoch, (u32)(k + 1));
    }
}

// ---------------------------------------------------------------------------
// outgemm: out = relu(H) @ WoT + bo ; M=12288, N=64, K=1024. Separate
// dispatch (kernel boundary provides Hbuf coherence).
// ---------------------------------------------------------------------------
__global__ __launch_bounds__(256) void outgemm(
    const short* __restrict__ Hbuf, const short* __restrict__ WoT,
    const float* __restrict__ bo, float* __restrict__ out) {
    const int w = threadIdx.x >> 6, l = threadIdx.x & 63;
    const int lr = l & 15, kg = l >> 4;
    const int m0 = blockIdx.x * 64 + w * 16;
    const int arow = m0 + lr;

    f32x4 acc[4] = {{0.f,0.f,0.f,0.f},{0.f,0.f,0.f,0.f},
                    {0.f,0.f,0.f,0.f},{0.f,0.f,0.f,0.f}};
    const short* ap = Hbuf + (size_t)arow * HD + kg * 8;
    const short* bp = WoT + (size_t)lr * HD + kg * 8;
#pragma unroll 4
    for (int k0 = 0; k0 < HD; k0 += 32) {
        const short8 a = *reinterpret_cast<const short8*>(ap + k0);
#pragma unroll
        for (int c = 0; c < 4; ++c) {
            const short8 b = *reinterpret_cast<const short8*>(bp + (size_t)c * 16 * HD + k0);
            acc[c] = __builtin_amdgcn_mfma_f32_16x16x32_bf16(a, b, acc[c], 0, 0, 0);
        }
    }
    const int rb = m0 + kg * 4;
#pragma unroll
    for (int c = 0; c < 4; ++c) {
        const float bb = bo[c * 16 + lr];
#pragma unroll
        for (int r = 0; r < 4; ++r)
            out[(size_t)(rb + r) * F + c * 16 + lr] = acc[c][r] + bb;
    }
}

// ---------------------------------------------------------------------------
extern "C" void kernel_launch(void* const* d_in, const int* in_sizes, int n_in,
                              void* d_out, int out_size, void* d_ws, size_t ws_size,
                              hipStream_t stream) {
    const float* x   = (const float*)d_in[0];
    const float* Wh  = (const float*)d_in[1];
    const float* bh  = (const float*)d_in[2];
    const float* Wih = (const float*)d_in[3];
    const float* Whh = (const float*)d_in[4];
    const float* bih = (const float*)d_in[5];
    const float* bhh = (const float*)d_in[6];
    const float* Wo  = (const float*)d_in[7];
    const float* bo  = (const float*)d_in[8];
    float* out = (float*)d_out;

    char* p = (char*)d_ws;
    float* Wfold  = (float*)p; p += (size_t)F * HD * 4;
    float* bf0    = (float*)p; p += HD * 4;
    float* bf1    = (float*)p; p += HD * 4;
    short* WfoldT = (short*)p; p += (size_t)HD * F * 2;
    short* WhhT0  = (short*)p; p += (size_t)HD * HD * 2;
    short* WihT1  = (short*)p; p += (size_t)HD * HD * 2;
    short* WhhT1  = (short*)p; p += (size_t)HD * HD * 2;
    short* WoT    = (short*)p; p += (size_t)F * HD * 2;
    short* h0p0   = (short*)p; p += (size_t)B * HD * 2;
    short* h0p1   = (short*)p; p += (size_t)B * HD * 2;
    short* h1p0   = (short*)p; p += (size_t)B * HD * 2;
    short* h1p1   = (short*)p; p += (size_t)B * HD * 2;
    short* Hbuf   = (short*)p; p += (size_t)B * PRED * HD * 2;
    short* xbf    = (short*)p; p += (size_t)B * S * F * 2;
    u32*   sync   = (u32*)p;  p += 256;           // [0]=ctr, [64]=epoch

    hipMemsetAsync(sync, 0, 256, stream);

    fold_kernel<<<64, 256, 0, stream>>>(Wh, Wih, Wfold);
    bias_kernel<<<4, 256, 0, stream>>>(bh, Wih, bih, bhh, bf0, bf1);
    transpose_cast<<<16, 256, 0, stream>>>(Wfold, WfoldT, F, HD);
    transpose_cast<<<256, 256, 0, stream>>>(Whh, WhhT0, HD, HD);
    transpose_cast<<<256, 256, 0, stream>>>(Wih + (size_t)HD * HD, WihT1, HD, HD);
    transpose_cast<<<256, 256, 0, stream>>>(Whh + (size_t)HD * HD, WhhT1, HD, HD);
    transpose_cast<<<16, 256, 0, stream>>>(Wo, WoT, HD, F);
    xcast<<<(B * S * F) / (256 * 4), 256, 0, stream>>>(x, xbf);

    u32* ctr   = sync;
    u32* epoch = sync + 64;
    void* args[] = {
        (void*)&xbf, (void*)&WfoldT, (void*)&bf0, (void*)&WhhT0,
        (void*)&WihT1, (void*)&WhhT1, (void*)&bf1,
        (void*)&h0p0, (void*)&h0p1, (void*)&h1p0, (void*)&h1p1,
        (void*)&Hbuf, (void*)&ctr, (void*)&epoch
    };
    hipLaunchCooperativeKernel((void*)rnn_persistent, dim3(NBLK), dim3(512),
                               args, 0, stream);

    outgemm<<<192, 256, 0, stream>>>(Hbuf, WoT, bo, out);
}